// Round 11
// baseline (197.582 us; speedup 1.0000x reference)
//
#include <hip/hip_runtime.h>
#include <hip/hip_bf16.h>
#include <stdint.h>

#define N_GROUPS 368
#define NMODELS  64
#define BATCH    4096
#define ROWS     128   // batch rows per block (4 waves x 32)

typedef __attribute__((ext_vector_type(8)))  short short8v;  // 8 bf16 (4 VGPRs)
typedef __attribute__((ext_vector_type(16))) float f32x16;   // 32x32 MFMA acc

__device__ inline uint32_t f2u(float f) { return __builtin_bit_cast(uint32_t, f); }
__device__ inline float    u2f(uint32_t u) { return __builtin_bit_cast(float, u); }

// cheap split: hi = round-half-up bf16 (1 add + 1 and), lo = trunc bf16 of residual.
// residual error ~2^-17 rel; packs two bf16 per u32 (low short = first element).
__device__ inline void split4(const float4 v, uint2& hp, uint2& lp) {
    const uint32_t hx = (f2u(v.x) + 0x8000u) & 0xFFFF0000u;
    const uint32_t hy = (f2u(v.y) + 0x8000u) & 0xFFFF0000u;
    const uint32_t hz = (f2u(v.z) + 0x8000u) & 0xFFFF0000u;
    const uint32_t hw = (f2u(v.w) + 0x8000u) & 0xFFFF0000u;
    hp.x = (hx >> 16) | hy;
    hp.y = (hz >> 16) | hw;
    lp.x = (f2u(v.x - u2f(hx)) >> 16) | (f2u(v.y - u2f(hy)) & 0xFFFF0000u);
    lp.y = (f2u(v.z - u2f(hz)) >> 16) | (f2u(v.w - u2f(hw)) & 0xFFFF0000u);
}

// two float4 -> hi/lo bf16x8 fragments
__device__ inline void split8(const float4 a, const float4 b, short8v& h, short8v& l) {
    uint2 ha, la, hb, lb;
    split4(a, ha, la);
    split4(b, hb, lb);
    const uint4 hu = make_uint4(ha.x, ha.y, hb.x, hb.y);
    const uint4 lu = make_uint4(la.x, la.y, lb.x, lb.y);
    h = __builtin_bit_cast(short8v, hu);
    l = __builtin_bit_cast(short8v, lu);
}

// XOR swizzle on row-relative SHORT offset (flips 16B..64B slot bits).
// Same involution on write and read (verified passing in R7/R8).
#define SWZ(row, soff) ((soff) ^ (((row) & 7) << 3))

__global__ __launch_bounds__(256, 3) void ensemble_nobar(
    const float* __restrict__ x,     // [BATCH][N_GROUPS][NMODELS]
    const float* __restrict__ W,     // [N_GROUPS][NMODELS][NMODELS]
    const float* __restrict__ bias,  // [N_GROUPS][NMODELS]
    float* __restrict__ out)         // [BATCH][N_GROUPS]
{
    __shared__ __hip_bfloat16 Wh[64 * 64];  // 8 KB (swizzled)
    __shared__ __hip_bfloat16 Wl[64 * 64];  // 8 KB -> only 16 KB LDS total

    const int g    = blockIdx.y;
    const int row0 = blockIdx.x * ROWS;
    const int t    = threadIdx.x;

    // ---- stage W[g] -> LDS hi/lo (the ONLY barrier in the kernel) ----
    {
        const int wm = t >> 2;           // W row 0..63
        const int wc = (t & 3) * 16;     // 16 floats per thread
        const float* __restrict__ Wgp =
            W + (size_t)g * (NMODELS * NMODELS) + (size_t)wm * NMODELS + wc;
        #pragma unroll
        for (int j = 0; j < 4; ++j) {
            const float4 v = *reinterpret_cast<const float4*>(Wgp + 4 * j);
            uint2 hp, lp; split4(v, hp, lp);
            const int so = wm * 64 + SWZ(wm, wc + 4 * j);
            *reinterpret_cast<uint2*>(&Wh[so]) = hp;
            *reinterpret_cast<uint2*>(&Wl[so]) = lp;
        }
    }
    __syncthreads();

    const int lane = t & 63;
    const int wv   = t >> 6;      // wave id -> batch-row tile [wv*32, wv*32+32)
    const int cl   = lane & 31;
    const int h2   = lane >> 5;
    const int c    = wv * 32 + cl;   // this lane's batch row

    const float* __restrict__ xr =
        x + ((size_t)(row0 + c) * N_GROUPS + g) * NMODELS;

    // ---- MFMA: Y^T = W . X^T ; B-frags loaded DIRECTLY from global ----
    f32x16 acc0, acc1;
    #pragma unroll
    for (int r = 0; r < 16; ++r) { acc0[r] = 0.f; acc1[r] = 0.f; }

    #pragma unroll
    for (int ks = 0; ks < 4; ++ks) {
        const int ko = ks * 16 + 8 * h2;
        // x[c][ko..ko+7]: 32B contiguous -> bf16 hi/lo fragments in-register
        const float4 xa = *reinterpret_cast<const float4*>(xr + ko);
        const float4 xb = *reinterpret_cast<const float4*>(xr + ko + 4);
        short8v bh, bl; split8(xa, xb, bh, bl);

        const int wo0 = cl * 64 + SWZ(cl, ko);          // tile 0: m = cl
        const short8v ah0 = *reinterpret_cast<const short8v*>(&Wh[wo0]);
        const short8v al0 = *reinterpret_cast<const short8v*>(&Wl[wo0]);
        acc0 = __builtin_amdgcn_mfma_f32_32x32x16_bf16(ah0, bh, acc0, 0, 0, 0);
        acc0 = __builtin_amdgcn_mfma_f32_32x32x16_bf16(ah0, bl, acc0, 0, 0, 0);
        acc0 = __builtin_amdgcn_mfma_f32_32x32x16_bf16(al0, bh, acc0, 0, 0, 0);

        const int m1  = 32 + cl;                        // tile 1: m = 32+cl
        const int wo1 = m1 * 64 + SWZ(m1, ko);
        const short8v ah1 = *reinterpret_cast<const short8v*>(&Wh[wo1]);
        const short8v al1 = *reinterpret_cast<const short8v*>(&Wl[wo1]);
        acc1 = __builtin_amdgcn_mfma_f32_32x32x16_bf16(ah1, bh, acc1, 0, 0, 0);
        acc1 = __builtin_amdgcn_mfma_f32_32x32x16_bf16(ah1, bl, acc1, 0, 0, 0);
        acc1 = __builtin_amdgcn_mfma_f32_32x32x16_bf16(al1, bh, acc1, 0, 0, 0);
    }

    // ---- bias (8 float4 loads, L2-hot) ----
    // lane's m-slots: m = tt*32 + 8*rq + 4*h2 + p ; acc reg r = 4*rq + p
    float4 bv4[2][4];
    #pragma unroll
    for (int tt = 0; tt < 2; ++tt)
        #pragma unroll
        for (int rq = 0; rq < 4; ++rq)
            bv4[tt][rq] = *reinterpret_cast<const float4*>(
                bias + (size_t)g * 64 + tt * 32 + 8 * rq + 4 * h2);

    // ---- epilogue: softmax over m (in-register) + dot with raw fp32 x ----
    float y[2][16];
    #pragma unroll
    for (int tt = 0; tt < 2; ++tt)
        #pragma unroll
        for (int rq = 0; rq < 4; ++rq) {
            const f32x16& a = tt ? acc1 : acc0;
            y[tt][4*rq+0] = a[4*rq+0] + bv4[tt][rq].x;
            y[tt][4*rq+1] = a[4*rq+1] + bv4[tt][rq].y;
            y[tt][4*rq+2] = a[4*rq+2] + bv4[tt][rq].z;
            y[tt][4*rq+3] = a[4*rq+3] + bv4[tt][rq].w;
        }

    float mx = y[0][0];
    #pragma unroll
    for (int r = 1; r < 16; ++r) mx = fmaxf(mx, y[0][r]);
    #pragma unroll
    for (int r = 0; r < 16; ++r) mx = fmaxf(mx, y[1][r]);
    mx = fmaxf(mx, __shfl_xor(mx, 32));

    float S = 0.f, P = 0.f;
    #pragma unroll
    for (int tt = 0; tt < 2; ++tt)
        #pragma unroll
        for (int j = 0; j < 4; ++j) {
            // x[c][m] for m = tt*32 + 8j + 4*h2 .. +3 : fp32, L1/L2-hot
            const float4 xv4 = *reinterpret_cast<const float4*>(
                xr + tt * 32 + 8 * j + 4 * h2);
            const float e0 = __expf(y[tt][4*j+0] - mx);
            const float e1 = __expf(y[tt][4*j+1] - mx);
            const float e2 = __expf(y[tt][4*j+2] - mx);
            const float e3 = __expf(y[tt][4*j+3] - mx);
            S += (e0 + e1) + (e2 + e3);
            P = __builtin_fmaf(e0, xv4.x, P);
            P = __builtin_fmaf(e1, xv4.y, P);
            P = __builtin_fmaf(e2, xv4.z, P);
            P = __builtin_fmaf(e3, xv4.w, P);
        }
    S += __shfl_xor(S, 32);
    P += __shfl_xor(P, 32);

    if (h2 == 0)
        out[(size_t)(row0 + c) * N_GROUPS + g] = P / S;
}

extern "C" void kernel_launch(void* const* d_in, const int* in_sizes, int n_in,
                              void* d_out, int out_size, void* d_ws, size_t ws_size,
                              hipStream_t stream) {
    const float* x  = (const float*)d_in[0];
    const float* W  = (const float*)d_in[1];
    const float* b  = (const float*)d_in[2];
    float* out = (float*)d_out;

    dim3 grid(BATCH / ROWS, N_GROUPS);   // (32, 368)
    dim3 block(256);
    ensemble_nobar<<<grid, block, 0, stream>>>(x, W, b, out);
}

// Round 12
// 185.421 us; speedup vs baseline: 1.0656x; 1.0656x over previous
//
#include <hip/hip_runtime.h>
#include <hip/hip_bf16.h>
#include <stdint.h>

#define N_GROUPS 368
#define NMODELS  64
#define BATCH    4096
#define ROWS     128   // batch rows per block (4 waves x 32)

typedef __attribute__((ext_vector_type(8)))  short short8v;  // 8 bf16 (4 VGPRs)
typedef __attribute__((ext_vector_type(16))) float f32x16;   // 32x32 MFMA acc

__device__ inline uint32_t f2u(float f) { return __builtin_bit_cast(uint32_t, f); }
__device__ inline float    u2f(uint32_t u) { return __builtin_bit_cast(float, u); }

// cheap split: hi = round-half-up bf16, lo = trunc bf16 of residual (~2^-17 rel).
__device__ inline void split4(const float4 v, uint2& hp, uint2& lp) {
    const uint32_t hx = (f2u(v.x) + 0x8000u) & 0xFFFF0000u;
    const uint32_t hy = (f2u(v.y) + 0x8000u) & 0xFFFF0000u;
    const uint32_t hz = (f2u(v.z) + 0x8000u) & 0xFFFF0000u;
    const uint32_t hw = (f2u(v.w) + 0x8000u) & 0xFFFF0000u;
    hp.x = (hx >> 16) | hy;
    hp.y = (hz >> 16) | hw;
    lp.x = (f2u(v.x - u2f(hx)) >> 16) | (f2u(v.y - u2f(hy)) & 0xFFFF0000u);
    lp.y = (f2u(v.z - u2f(hz)) >> 16) | (f2u(v.w - u2f(hw)) & 0xFFFF0000u);
}

// two float4 -> hi/lo bf16x8 fragments
__device__ inline void split8(const float4 a, const float4 b, short8v& h, short8v& l) {
    uint2 ha, la, hb, lb;
    split4(a, ha, la);
    split4(b, hb, lb);
    const uint4 hu = make_uint4(ha.x, ha.y, hb.x, hb.y);
    const uint4 lu = make_uint4(la.x, la.y, lb.x, lb.y);
    h = __builtin_bit_cast(short8v, hu);
    l = __builtin_bit_cast(short8v, lu);
}

// XOR swizzle on row-relative SHORT offset (verified involution, R7/R8/R11 pass)
#define SWZ(row, soff) ((soff) ^ (((row) & 7) << 3))

__global__ __launch_bounds__(256, 3) void ensemble_burst(
    const float* __restrict__ x,     // [BATCH][N_GROUPS][NMODELS]
    const float* __restrict__ W,     // [N_GROUPS][NMODELS][NMODELS]
    const float* __restrict__ bias,  // [N_GROUPS][NMODELS]
    float* __restrict__ out)         // [BATCH][N_GROUPS]
{
    __shared__ __hip_bfloat16 Wh[64 * 64];  // 8 KB (swizzled)
    __shared__ __hip_bfloat16 Wl[64 * 64];  // 8 KB -> 16 KB LDS total

    const int g    = blockIdx.y;
    const int row0 = blockIdx.x * ROWS;
    const int t    = threadIdx.x;

    // ---- stage W[g] -> LDS hi/lo (the ONLY barrier in the kernel) ----
    {
        const int wm = t >> 2;           // W row 0..63
        const int wc = (t & 3) * 16;     // 16 floats per thread
        const float* __restrict__ Wgp =
            W + (size_t)g * (NMODELS * NMODELS) + (size_t)wm * NMODELS + wc;
        #pragma unroll
        for (int j = 0; j < 4; ++j) {
            const float4 v = *reinterpret_cast<const float4*>(Wgp + 4 * j);
            uint2 hp, lp; split4(v, hp, lp);
            const int so = wm * 64 + SWZ(wm, wc + 4 * j);
            *reinterpret_cast<uint2*>(&Wh[so]) = hp;
            *reinterpret_cast<uint2*>(&Wl[so]) = lp;
        }
    }
    __syncthreads();

    const int lane = t & 63;
    const int wv   = t >> 6;      // wave id -> batch-row tile [wv*32, wv*32+32)
    const int cl   = lane & 31;
    const int h2   = lane >> 5;
    const int c    = wv * 32 + cl;   // lanes l and l+32 share row c (different k-half)

    const float* __restrict__ xr =
        x + ((size_t)(row0 + c) * N_GROUPS + g) * NMODELS;

    // ---- BURST: issue ALL x loads up front (16 independent float4/lane) ----
    // MFMA frag set: floats [8*h2 + 16*ks, +8)  -> base pm = xr + 8*h2
    // epilogue set:  floats [4*h2 + 8*j', +4)   -> base pe = xr + 4*h2
    const float* pm = xr + 8 * h2;
    const float* pe = xr + 4 * h2;
    float4 fq[8];
    #pragma unroll
    for (int ks = 0; ks < 4; ++ks) {
        fq[2*ks]   = *reinterpret_cast<const float4*>(pm + 16 * ks);
        fq[2*ks+1] = *reinterpret_cast<const float4*>(pm + 16 * ks + 4);
    }
    float4 pq[8];
    #pragma unroll
    for (int j = 0; j < 8; ++j)
        pq[j] = *reinterpret_cast<const float4*>(pe + 8 * j);

    // ---- MFMA: Y^T = W . X^T ----
    f32x16 acc0, acc1;
    #pragma unroll
    for (int r = 0; r < 16; ++r) { acc0[r] = 0.f; acc1[r] = 0.f; }

    #pragma unroll
    for (int ks = 0; ks < 4; ++ks) {
        const int ko = ks * 16 + 8 * h2;
        short8v bh, bl; split8(fq[2*ks], fq[2*ks+1], bh, bl);

        const int wo0 = cl * 64 + SWZ(cl, ko);          // tile 0: m = cl
        const short8v ah0 = *reinterpret_cast<const short8v*>(&Wh[wo0]);
        const short8v al0 = *reinterpret_cast<const short8v*>(&Wl[wo0]);
        acc0 = __builtin_amdgcn_mfma_f32_32x32x16_bf16(ah0, bh, acc0, 0, 0, 0);
        acc0 = __builtin_amdgcn_mfma_f32_32x32x16_bf16(ah0, bl, acc0, 0, 0, 0);
        acc0 = __builtin_amdgcn_mfma_f32_32x32x16_bf16(al0, bh, acc0, 0, 0, 0);

        const int m1  = 32 + cl;                        // tile 1: m = 32+cl
        const int wo1 = m1 * 64 + SWZ(m1, ko);
        const short8v ah1 = *reinterpret_cast<const short8v*>(&Wh[wo1]);
        const short8v al1 = *reinterpret_cast<const short8v*>(&Wl[wo1]);
        acc1 = __builtin_amdgcn_mfma_f32_32x32x16_bf16(ah1, bh, acc1, 0, 0, 0);
        acc1 = __builtin_amdgcn_mfma_f32_32x32x16_bf16(ah1, bl, acc1, 0, 0, 0);
        acc1 = __builtin_amdgcn_mfma_f32_32x32x16_bf16(al1, bh, acc1, 0, 0, 0);
    }

    // ---- bias (8 float4 loads, L2-hot) ----
    // lane's m-slots: m = tt*32 + 8*rq + 4*h2 + p ; acc reg r = 4*rq + p
    float4 bv4[2][4];
    #pragma unroll
    for (int tt = 0; tt < 2; ++tt)
        #pragma unroll
        for (int rq = 0; rq < 4; ++rq)
            bv4[tt][rq] = *reinterpret_cast<const float4*>(
                bias + (size_t)g * 64 + tt * 32 + 8 * rq + 4 * h2);

    // ---- epilogue: softmax over m (in-register) + dot with reg-resident x ----
    float y[2][16];
    #pragma unroll
    for (int tt = 0; tt < 2; ++tt)
        #pragma unroll
        for (int rq = 0; rq < 4; ++rq) {
            const f32x16& a = tt ? acc1 : acc0;
            y[tt][4*rq+0] = a[4*rq+0] + bv4[tt][rq].x;
            y[tt][4*rq+1] = a[4*rq+1] + bv4[tt][rq].y;
            y[tt][4*rq+2] = a[4*rq+2] + bv4[tt][rq].z;
            y[tt][4*rq+3] = a[4*rq+3] + bv4[tt][rq].w;
        }

    float mx = y[0][0];
    #pragma unroll
    for (int r = 1; r < 16; ++r) mx = fmaxf(mx, y[0][r]);
    #pragma unroll
    for (int r = 0; r < 16; ++r) mx = fmaxf(mx, y[1][r]);
    mx = fmaxf(mx, __shfl_xor(mx, 32));

    float S = 0.f, P = 0.f;
    #pragma unroll
    for (int tt = 0; tt < 2; ++tt)
        #pragma unroll
        for (int rq = 0; rq < 4; ++rq) {
            // x[c][m] for m = tt*32 + 8*rq + 4*h2 .. +3 : in registers (pq)
            const float4 xv4 = pq[4*tt + rq];
            const float e0 = __expf(y[tt][4*rq+0] - mx);
            const float e1 = __expf(y[tt][4*rq+1] - mx);
            const float e2 = __expf(y[tt][4*rq+2] - mx);
            const float e3 = __expf(y[tt][4*rq+3] - mx);
            S += (e0 + e1) + (e2 + e3);
            P = __builtin_fmaf(e0, xv4.x, P);
            P = __builtin_fmaf(e1, xv4.y, P);
            P = __builtin_fmaf(e2, xv4.z, P);
            P = __builtin_fmaf(e3, xv4.w, P);
        }
    S += __shfl_xor(S, 32);
    P += __shfl_xor(P, 32);

    if (h2 == 0)
        out[(size_t)(row0 + c) * N_GROUPS + g] = P / S;
}

extern "C" void kernel_launch(void* const* d_in, const int* in_sizes, int n_in,
                              void* d_out, int out_size, void* d_ws, size_t ws_size,
                              hipStream_t stream) {
    const float* x  = (const float*)d_in[0];
    const float* W  = (const float*)d_in[1];
    const float* b  = (const float*)d_in[2];
    float* out = (float*)d_out;

    dim3 grid(BATCH / ROWS, N_GROUPS);   // (32, 368)
    dim3 block(256);
    ensemble_burst<<<grid, block, 0, stream>>>(x, W, b, out);
}

// Round 13
// 153.640 us; speedup vs baseline: 1.2860x; 1.2069x over previous
//
#include <hip/hip_runtime.h>
#include <hip/hip_bf16.h>
#include <hip/hip_fp16.h>
#include <stdint.h>

#define N_GROUPS 368
#define NMODELS  64
#define BATCH    4096
#define RPB      128   // batch rows per block
#define GPB      2     // groups per block (contiguous pair -> 512B/row granule)

typedef __attribute__((ext_vector_type(8)))  _Float16 half8v;  // 8 fp16 (4 VGPRs)
typedef __attribute__((ext_vector_type(4)))  _Float16 half4v;
typedef __attribute__((ext_vector_type(16))) float    f32x16;  // 32x32 MFMA acc

// XOR swizzle on row-relative SHORT offset (flips 16B..64B slot bits).
// Same involution on write and read (verified in R7/R8/R11).
#define SWZ(row, soff) ((soff) ^ (((row) & 7) << 3))

__global__ __launch_bounds__(512, 4) void ensemble_pair(
    const float* __restrict__ x,     // [BATCH][N_GROUPS][NMODELS]
    const float* __restrict__ W,     // [N_GROUPS][NMODELS][NMODELS]
    const float* __restrict__ bias,  // [N_GROUPS][NMODELS]
    float* __restrict__ out)         // [BATCH][N_GROUPS]
{
    __shared__ _Float16 Xh[GPB][RPB * 64];  // 32 KB (fp16 hi of x)
    __shared__ _Float16 Wh[GPB][64 * 64];   // 16 KB (fp16 hi of W)
    __shared__ _Float16 Wl[GPB][64 * 64];   // 16 KB (fp16 residual of W) -> 64 KB, 2/CU

    const int g0   = blockIdx.y * GPB;
    const int row0 = blockIdx.x * RPB;
    const int t    = threadIdx.x;

    // ---- stage X: 128 rows x 512B contiguous (2 groups) -> fp16 hi ----
    #pragma unroll
    for (int j = 0; j < 8; ++j) {
        const int r   = (t >> 5) + 16 * j;   // row 0..127
        const int col = (t & 31) * 4;        // float col within 128 (2 groups)
        const int gi  = col >> 6;
        const int k   = col & 63;
        const float4 v = *reinterpret_cast<const float4*>(
            x + ((size_t)(row0 + r) * N_GROUPS + g0) * NMODELS + col);
        half4v h;
        h[0] = (_Float16)v.x; h[1] = (_Float16)v.y;
        h[2] = (_Float16)v.z; h[3] = (_Float16)v.w;
        *reinterpret_cast<half4v*>(&Xh[gi][r * 64 + SWZ(r, k)]) = h;
    }

    // ---- stage W[g0..g0+1] -> fp16 hi + lo (2-product split) ----
    {
        const int gw = t >> 8;           // 0..1
        const int u  = t & 255;
        const int m  = u >> 2;           // W row 0..63
        const int wc = (u & 3) * 16;     // 16 floats
        const float* __restrict__ Wgp =
            W + ((size_t)(g0 + gw) * 64 + m) * 64 + wc;
        #pragma unroll
        for (int j = 0; j < 4; ++j) {
            const float4 v = *reinterpret_cast<const float4*>(Wgp + 4 * j);
            half4v hh, hl;
            {
                const _Float16 a = (_Float16)v.x; hh[0] = a; hl[0] = (_Float16)(v.x - (float)a);
                const _Float16 b = (_Float16)v.y; hh[1] = b; hl[1] = (_Float16)(v.y - (float)b);
                const _Float16 c = (_Float16)v.z; hh[2] = c; hl[2] = (_Float16)(v.z - (float)c);
                const _Float16 d = (_Float16)v.w; hh[3] = d; hl[3] = (_Float16)(v.w - (float)d);
            }
            const int so = m * 64 + SWZ(m, wc + 4 * j);
            *reinterpret_cast<half4v*>(&Wh[gw][so]) = hh;
            *reinterpret_cast<half4v*>(&Wl[gw][so]) = hl;
        }
    }
    __syncthreads();

    const int lane = t & 63;
    const int wv   = t >> 6;       // 8 waves
    const int gw2  = wv >> 2;      // group for this wave
    const int rt   = wv & 3;       // row-tile within group
    const int cl   = lane & 31;
    const int h2   = lane >> 5;
    const int cloc = rt * 32 + cl; // local batch row 0..127
    const int g    = g0 + gw2;

    // ---- MFMA: Y^T = (Wh+Wl) . Xh^T  (fp16 2-product) ----
    f32x16 acc0, acc1;
    #pragma unroll
    for (int r = 0; r < 16; ++r) { acc0[r] = 0.f; acc1[r] = 0.f; }

    #pragma unroll
    for (int ks = 0; ks < 4; ++ks) {
        const int ko = ks * 16 + 8 * h2;
        const half8v bh = *reinterpret_cast<const half8v*>(
            &Xh[gw2][cloc * 64 + SWZ(cloc, ko)]);

        const int wo0 = cl * 64 + SWZ(cl, ko);          // tile 0: m = cl
        const half8v ah0 = *reinterpret_cast<const half8v*>(&Wh[gw2][wo0]);
        const half8v al0 = *reinterpret_cast<const half8v*>(&Wl[gw2][wo0]);
        acc0 = __builtin_amdgcn_mfma_f32_32x32x16_f16(ah0, bh, acc0, 0, 0, 0);
        acc0 = __builtin_amdgcn_mfma_f32_32x32x16_f16(al0, bh, acc0, 0, 0, 0);

        const int wo1 = (32 + cl) * 64 + SWZ(32 + cl, ko);  // tile 1: m = 32+cl
        const half8v ah1 = *reinterpret_cast<const half8v*>(&Wh[gw2][wo1]);
        const half8v al1 = *reinterpret_cast<const half8v*>(&Wl[gw2][wo1]);
        acc1 = __builtin_amdgcn_mfma_f32_32x32x16_f16(ah1, bh, acc1, 0, 0, 0);
        acc1 = __builtin_amdgcn_mfma_f32_32x32x16_f16(al1, bh, acc1, 0, 0, 0);
    }

    // ---- bias consumed inline (no persistent array) ----
    // lane's m-slots: m = tt*32 + 8*rq + 4*h2 + p ; acc reg r = 4*rq + p
    float y[2][16];
    #pragma unroll
    for (int tt = 0; tt < 2; ++tt)
        #pragma unroll
        for (int rq = 0; rq < 4; ++rq) {
            const float4 bv = *reinterpret_cast<const float4*>(
                bias + (size_t)g * 64 + tt * 32 + 8 * rq + 4 * h2);
            const f32x16& a = tt ? acc1 : acc0;
            y[tt][4*rq+0] = a[4*rq+0] + bv.x;
            y[tt][4*rq+1] = a[4*rq+1] + bv.y;
            y[tt][4*rq+2] = a[4*rq+2] + bv.z;
            y[tt][4*rq+3] = a[4*rq+3] + bv.w;
        }

    // ---- softmax over m (in-register; halves joined by one shfl) ----
    float mx = y[0][0];
    #pragma unroll
    for (int r = 1; r < 16; ++r) mx = fmaxf(mx, y[0][r]);
    #pragma unroll
    for (int r = 0; r < 16; ++r) mx = fmaxf(mx, y[1][r]);
    mx = fmaxf(mx, __shfl_xor(mx, 32));

    const float* __restrict__ xr =
        x + ((size_t)(row0 + cloc) * N_GROUPS + g) * NMODELS;

    float S = 0.f, P = 0.f;
    #pragma unroll
    for (int tt = 0; tt < 2; ++tt)
        #pragma unroll
        for (int rq = 0; rq < 4; ++rq) {
            // x[c][m] for m = tt*32 + 8*rq + 4*h2 .. +3 : raw fp32, L1/L2-hot
            const float4 xv4 = *reinterpret_cast<const float4*>(
                xr + tt * 32 + 8 * rq + 4 * h2);
            const float e0 = __expf(y[tt][4*rq+0] - mx);
            const float e1 = __expf(y[tt][4*rq+1] - mx);
            const float e2 = __expf(y[tt][4*rq+2] - mx);
            const float e3 = __expf(y[tt][4*rq+3] - mx);
            S += (e0 + e1) + (e2 + e3);
            P = __builtin_fmaf(e0, xv4.x, P);
            P = __builtin_fmaf(e1, xv4.y, P);
            P = __builtin_fmaf(e2, xv4.z, P);
            P = __builtin_fmaf(e3, xv4.w, P);
        }
    S += __shfl_xor(S, 32);
    P += __shfl_xor(P, 32);

    if (h2 == 0)
        out[(size_t)(row0 + cloc) * N_GROUPS + g] = P / S;
}

extern "C" void kernel_launch(void* const* d_in, const int* in_sizes, int n_in,
                              void* d_out, int out_size, void* d_ws, size_t ws_size,
                              hipStream_t stream) {
    const float* x  = (const float*)d_in[0];
    const float* W  = (const float*)d_in[1];
    const float* b  = (const float*)d_in[2];
    float* out = (float*)d_out;

    dim3 grid(BATCH / RPB, N_GROUPS / GPB);   // (32, 184)
    dim3 block(512);
    ensemble_pair<<<grid, block, 0, stream>>>(x, W, b, out);
}